// Round 2
// baseline (582.877 us; speedup 1.0000x reference)
//
#include <hip/hip_runtime.h>
#include <stdint.h>
#include <math.h>

#define BATCH 131072
#define WS_TN_OFF 65536
#define WS_B_OFF  65544   // 6 x 64 floats: nb1,nb2,ab1,ab2,ob1,ob2 ; tvec at +1536 bytes

typedef __attribute__((ext_vector_type(8)))  short short8;   // 8 bf16
typedef __attribute__((ext_vector_type(16))) float float16;  // MFMA 32x32 acc
typedef __attribute__((ext_vector_type(2)))  unsigned int uint2v;

union S8 { short8 s; uint32_t u[4]; };
union F8 { float f[8]; uint32_t u[8]; float4 v4[2]; };

// ---------------- prep: weights -> bf16 (RNE) frag order; biases + tvec + |tvec| ----------------
// Frag layout (identical for A- and B-operand use of mfma_f32_32x32x16_bf16):
// lane -> n = nt*32+(lane&31); k = kc*16 + (lane>>5)*8 + j.
// ws: u*8192 + (kc*2+nt)*1024 + lane*16 + j*2. units u: 0=nW1 1=nW2 2=aW1[0:64] 3=aW1[64:128]
// 4=aW2 5=oW1[0:64] 6=oW1[64:128] 7=oW2
__global__ __launch_bounds__(256)
void prep_kernel(const float* __restrict__ tvec,
                 const float* __restrict__ nW1, const float* __restrict__ nW2,
                 const float* __restrict__ aW1, const float* __restrict__ aW2,
                 const float* __restrict__ oW1, const float* __restrict__ oW2,
                 const float* __restrict__ nb1, const float* __restrict__ nb2,
                 const float* __restrict__ ab1, const float* __restrict__ ab2,
                 const float* __restrict__ ob1, const float* __restrict__ ob2,
                 char* __restrict__ ws)
{
    const int id = blockIdx.x * 256 + threadIdx.x;
    if (id == 0) {
        float s = 0.f;
        for (int j = 0; j < 64; ++j) s = fmaf(tvec[j], tvec[j], s);
        *(float*)(ws + WS_TN_OFF) = fmaxf(sqrtf(s), 1e-8f);
    }
    if (id < 32768) {
        const float* srcs[8] = { nW1, nW2, aW1, aW1 + 4096, aW2, oW1, oW1 + 4096, oW2 };
        const int u    = id >> 12;
        const int e    = id & 4095;
        const int j    = e & 7;
        const int lane = (e >> 3) & 63;
        const int f    = e >> 9;          // kc*2 + nt
        const int nt   = f & 1, kc = f >> 1;
        const int k    = kc * 16 + (lane >> 5) * 8 + j;
        const int n    = nt * 32 + (lane & 31);
        const uint32_t b = __float_as_uint(srcs[u][k * 64 + n]);
        const uint32_t r = b + 0x7fffu + ((b >> 16) & 1u);   // RNE to bf16
        ((uint16_t*)(ws + u * 8192 + f * 1024 + lane * 16))[j] = (uint16_t)(r >> 16);
    } else if (id < 33152) {
        const int b   = id - 32768;       // 0..383
        const int arr = b >> 6, j = b & 63;
        const float* bp = (arr == 0) ? nb1 : (arr == 1) ? nb2 : (arr == 2) ? ab1
                        : (arr == 3) ? ab2 : (arr == 4) ? ob1 : ob2;
        ((float*)(ws + WS_B_OFF))[b] = bp[j];
    } else if (id < 33216) {
        const int j = id - 33152;         // 0..63: tvec copy
        ((float*)(ws + WS_B_OFF + 1536))[j] = tvec[j];
    }
}

// ---------------- main kernel: transposed MFMA (Y^T = W^T @ X^T), register dataflow +
//                  one-op-ahead gather prefetch + per-wave LDS slots for stored frags ----------
// op word: g(0:2) | u(3:5) | sH(6) | init(7) | bid(8:10) | epi(11:12) | red(13:14) | slot(15)
//          | pg(16:18) | alt(19)
// g : 0 none, else PACK prefetched gather buffer -> X frags (alt: from gx2)
// pg: 0 none, 1..5 issue gather of seq[:,pg-1], 6 pos_target, 7 neg_target  (into gx, AFTER MFMA)
// sH: consume stored bf16 frag from LDS slot (sl: 0=i6, 1=enc) with 8 MFMA
// epi: 0 none, 1 act->X, 2 raw->X (hi/lo frags), 3 raw->LDS slot (bf16 RNE)
// red: 0 none, 1 reduce->out[pos], 2 reduce->out[neg]
#define OPW(g,u,sH,ini,bid,ep,rd,sl,pg,alt) \
    ((g)|((u)<<3)|((sH)<<6)|((ini)<<7)|((bid)<<8)|((ep)<<11)|((rd)<<13)|((sl)<<15)|((pg)<<16)|((alt)<<19))

__global__ __launch_bounds__(256, 4)
void logicnet_mfma(const int* __restrict__ seq, const int* __restrict__ post,
                   const int* __restrict__ negt, const float* __restrict__ E,
                   const char* __restrict__ ws, float* __restrict__ out)
{
    static const uint32_t PROG[24] = {
        OPW(0,5,0,1,4,0,0,0,0,0),  //  1: acc=ob1 + oW1[0:]^T@X(s2, packed in prologue)
        OPW(4,6,0,0,0,1,0,0,2,1),  //  2: pack s3(gx2); += oW1[64:]^T@X; issue s1; act->X=h(i6)
        OPW(0,7,0,1,5,3,0,0,0,0),  //  3: acc=ob2 + oW2^T@X, raw -> i6 slot (LDS)
        OPW(2,0,0,1,0,1,0,0,1,0),  //  4: pack s1; acc=nb1 + nW1^T@X; issue s0; act -> X
        OPW(0,1,0,1,1,2,0,0,0,0),  //  5: acc=nb2 + nW2^T@X, raw -> X = n1
        OPW(0,3,0,1,2,0,0,0,0,0),  //  6: acc=ab1 + aW1[64:]^T@n1
        OPW(1,2,0,0,0,1,0,0,0,0),  //  7: pack s0; += aW1[0:]^T@X, act -> X = h(i5)
        OPW(0,4,0,1,3,2,0,0,0,0),  //  8: acc=ab2 + aW2^T@X, raw -> X = i5
        OPW(0,2,0,1,2,0,0,0,0,0),  //  9: acc=ab1 + aW1[0:]^T@i5
        OPW(0,3,1,0,0,1,0,0,0,0),  // 10: += aW1[64:]^T@i6slot, act -> X = h(i7)
        OPW(0,4,0,1,3,2,0,0,0,0),  // 11: acc=ab2 + aW2^T@X, raw -> X = i7
        OPW(0,0,0,1,0,1,0,0,5,0),  // 12: acc=nb1 + nW1^T@X; issue s4; act -> X
        OPW(0,1,0,1,1,2,0,0,0,0),  // 13: acc=nb2 + nW2^T@X, raw -> X = n7
        OPW(0,5,0,1,4,0,0,0,0,0),  // 14: acc=ob1 + oW1[0:]^T@n7
        OPW(5,6,0,0,0,1,0,0,0,0),  // 15: pack s4; += oW1[64:]^T@X, act -> X
        OPW(0,7,0,1,5,2,0,0,0,0),  // 16: acc=ob2 + oW2^T@X, raw -> X = out8
        OPW(0,0,0,1,0,1,0,0,6,0),  // 17: acc=nb1 + nW1^T@X; issue ip; act -> X
        OPW(0,1,0,1,1,3,0,1,0,0),  // 18: acc=nb2 + nW2^T@X, raw -> enc slot (LDS)
        OPW(0,5,1,1,4,0,0,1,0,0),  // 19: acc=ob1 + oW1[0:]^T@encslot
        OPW(6,6,0,0,0,1,0,0,7,0),  // 20: pack ip; += oW1[64:]^T@X; issue im; act -> X
        OPW(0,7,0,1,5,0,1,0,0,0),  // 21: acc=ob2 + oW2^T@X, reduce -> out(pos)
        OPW(0,5,1,1,4,0,0,1,0,0),  // 22: acc=ob1 + oW1[0:]^T@encslot  (recompute)
        OPW(7,6,0,0,0,1,0,0,0,0),  // 23: pack im; += oW1[64:]^T@X, act -> X
        OPW(0,7,0,1,5,0,2,0,0,0),  // 24: acc=ob2 + oW2^T@X, reduce -> out(neg)
    };

    // LDS: biases[384] + tvec[64] + per-wave i6 slot (4 KB/wave) + per-wave enc slot (4 KB/wave)
    __shared__ uint32_t lds[448 + 4096 + 4096];   // 34.6 KB -> 4 blocks/CU
    const int tid  = threadIdx.x;
    const int wid  = tid >> 6;
    const int lane = tid & 63;
    const int m    = lane & 31;            // batch row within tile (= C column)
    const int h    = lane >> 5;            // half selector
    const int rowbase = (blockIdx.x * 4 + wid) * 32;
    const int rr   = rowbase + m;

    uint32_t* const slot0 = &lds[448 + wid * 1024];          // i6
    uint32_t* const slot1 = &lds[448 + 4096 + wid * 1024];   // enc
    const float* const ldsb = (const float*)lds;             // biases [6][64]
    const float* const ltv  = (const float*)(lds + 384);     // tvec [64]

    const int sv0 = seq[(size_t)rr * 5 + 0], sv1 = seq[(size_t)rr * 5 + 1];
    const int sv2 = seq[(size_t)rr * 5 + 2], sv3 = seq[(size_t)rr * 5 + 3];
    const int sv4 = seq[(size_t)rr * 5 + 4];
    const int ipv = post[rr], imv = negt[rr];

    float16 acc[2];                 // C layout: col = lane&31 = batch, row = feature
    S8 xhi[4], xlo[4];              // current X as B-frags (hi/lo fp32-emulation)
    F8 gx[4], gx2[4];               // raw gather prefetch buffers
    float tn;

    // issue 8x float4 loads of one embedding row slice into dst (no wait here)
    auto gissue = [&](F8* dst, int idx) {
        const float4* e = (const float4*)(E + (size_t)idx * 64 + h * 8);
#pragma unroll
        for (int kc = 0; kc < 4; ++kc) { dst[kc].v4[0] = e[kc * 4]; dst[kc].v4[1] = e[kc * 4 + 1]; }
    };
    // pack raw buffer -> xhi/xlo B-frags (hi = truncate, lo = residual)
    auto gpack = [&](const F8* src) {
#pragma unroll
        for (int kc = 0; kc < 4; ++kc) {
#pragma unroll
            for (int w = 0; w < 4; ++w) {
                const uint32_t b0 = src[kc].u[2 * w], b1 = src[kc].u[2 * w + 1];
                xhi[kc].u[w] = __builtin_amdgcn_perm(b1, b0, 0x07060302u);
                const float l0 = src[kc].f[2 * w]     - __uint_as_float(b0 & 0xffff0000u);
                const float l1 = src[kc].f[2 * w + 1] - __uint_as_float(b1 & 0xffff0000u);
                xlo[kc].u[w] = __builtin_amdgcn_perm(__float_as_uint(l1), __float_as_uint(l0), 0x07060302u);
            }
        }
    };

    // acc += W(u)^T @ X(hi|lo): 16 MFMA, W in the A slot, X in the B slot
    auto uaP = [&](int u) {
        const char* wb = ws + u * 8192 + lane * 16;
#pragma unroll
        for (int kc = 0; kc < 4; ++kc) {
            const short8 w0 = *(const short8*)(wb + (kc * 2 + 0) * 1024);
            const short8 w1 = *(const short8*)(wb + (kc * 2 + 1) * 1024);
            acc[0] = __builtin_amdgcn_mfma_f32_32x32x16_bf16(w0, xhi[kc].s, acc[0], 0, 0, 0);
            acc[1] = __builtin_amdgcn_mfma_f32_32x32x16_bf16(w1, xhi[kc].s, acc[1], 0, 0, 0);
            acc[0] = __builtin_amdgcn_mfma_f32_32x32x16_bf16(w0, xlo[kc].s, acc[0], 0, 0, 0);
            acc[1] = __builtin_amdgcn_mfma_f32_32x32x16_bf16(w1, xlo[kc].s, acc[1], 0, 0, 0);
        }
    };

    // acc += W(u)^T @ LDS-stored bf16 frag: 8 MFMA (kc-XOR swizzle caps bank conflict at 4-way)
    auto uaH = [&](int u, const uint32_t* slot) {
        const char* wb = ws + u * 8192 + lane * 16;
#pragma unroll
        for (int kc = 0; kc < 4; ++kc) {
            const short8 xf = *(const short8*)(slot + lane * 16 + ((kc ^ (lane & 3)) << 2));
            const short8 w0 = *(const short8*)(wb + (kc * 2 + 0) * 1024);
            const short8 w1 = *(const short8*)(wb + (kc * 2 + 1) * 1024);
            acc[0] = __builtin_amdgcn_mfma_f32_32x32x16_bf16(w0, xf, acc[0], 0, 0, 0);
            acc[1] = __builtin_amdgcn_mfma_f32_32x32x16_bf16(w1, xf, acc[1], 0, 0, 0);
        }
    };

    // C -> next B-frags, in-register (permlane32_swap pairs quads across the h-halves)
    auto epiX = [&](bool act) {
#pragma unroll
        for (int nt = 0; nt < 2; ++nt) {
#pragma unroll
            for (int c = 0; c < 2; ++c) {
                uint32_t ph[2][2], pl[2][2];
#pragma unroll
                for (int d = 0; d < 2; ++d) {
                    const int g2 = 2 * c + d;
                    float v0 = acc[nt][4 * g2 + 0], v1 = acc[nt][4 * g2 + 1];
                    float v2 = acc[nt][4 * g2 + 2], v3 = acc[nt][4 * g2 + 3];
                    if (act) {
                        v0 = fmaxf(v0, 0.01f * v0); v1 = fmaxf(v1, 0.01f * v1);
                        v2 = fmaxf(v2, 0.01f * v2); v3 = fmaxf(v3, 0.01f * v3);
                    }
                    const uint32_t b0 = __float_as_uint(v0), b1 = __float_as_uint(v1);
                    const uint32_t b2 = __float_as_uint(v2), b3 = __float_as_uint(v3);
                    ph[d][0] = __builtin_amdgcn_perm(b1, b0, 0x07060302u);
                    ph[d][1] = __builtin_amdgcn_perm(b3, b2, 0x07060302u);
                    const float l0 = v0 - __uint_as_float(b0 & 0xffff0000u);
                    const float l1 = v1 - __uint_as_float(b1 & 0xffff0000u);
                    const float l2 = v2 - __uint_as_float(b2 & 0xffff0000u);
                    const float l3 = v3 - __uint_as_float(b3 & 0xffff0000u);
                    pl[d][0] = __builtin_amdgcn_perm(__float_as_uint(l1), __float_as_uint(l0), 0x07060302u);
                    pl[d][1] = __builtin_amdgcn_perm(__float_as_uint(l3), __float_as_uint(l2), 0x07060302u);
                }
                const int kc = 2 * nt + c;
#pragma unroll
                for (int w = 0; w < 2; ++w) {
                    uint2v rh = __builtin_amdgcn_permlane32_swap(ph[0][w], ph[1][w], false, false);
                    xhi[kc].u[w]     = rh[0];
                    xhi[kc].u[2 + w] = rh[1];
                    uint2v rl = __builtin_amdgcn_permlane32_swap(pl[0][w], pl[1][w], false, false);
                    xlo[kc].u[w]     = rl[0];
                    xlo[kc].u[2 + w] = rl[1];
                }
            }
        }
    };

    // C -> stored bf16 frag (RNE) into per-wave LDS slot
    auto epiB = [&](uint32_t* slot) {
#pragma unroll
        for (int nt = 0; nt < 2; ++nt) {
#pragma unroll
            for (int c = 0; c < 2; ++c) {
                uint32_t pp[2][2];
#pragma unroll
                for (int d = 0; d < 2; ++d) {
                    const int g2 = 2 * c + d;
                    asm("v_cvt_pk_bf16_f32 %0, %1, %2"
                        : "=v"(pp[d][0]) : "v"(acc[nt][4 * g2 + 0]), "v"(acc[nt][4 * g2 + 1]));
                    asm("v_cvt_pk_bf16_f32 %0, %1, %2"
                        : "=v"(pp[d][1]) : "v"(acc[nt][4 * g2 + 2]), "v"(acc[nt][4 * g2 + 3]));
                }
                const int kc = 2 * nt + c;
                S8 o;
#pragma unroll
                for (int w = 0; w < 2; ++w) {
                    uint2v r = __builtin_amdgcn_permlane32_swap(pp[0][w], pp[1][w], false, false);
                    o.u[w]     = r[0];
                    o.u[2 + w] = r[1];
                }
                *(short8*)(slot + lane * 16 + ((kc ^ (lane & 3)) << 2)) = o.s;
            }
        }
    };

    // cosine head: lane already holds its batch row's features
    auto reduce = [&](float* outp) {
        float num = 0.f, ss = 0.f;
#pragma unroll
        for (int nt = 0; nt < 2; ++nt)
#pragma unroll
            for (int g2 = 0; g2 < 4; ++g2) {
                const float4 t4 = *(const float4*)(ltv + nt * 32 + g2 * 8 + h * 4);
                const float y0 = acc[nt][4 * g2 + 0], y1 = acc[nt][4 * g2 + 1];
                const float y2 = acc[nt][4 * g2 + 2], y3 = acc[nt][4 * g2 + 3];
                num = fmaf(y0, t4.x, fmaf(y1, t4.y, fmaf(y2, t4.z, fmaf(y3, t4.w, num))));
                ss  = fmaf(y0, y0, fmaf(y1, y1, fmaf(y2, y2, fmaf(y3, y3, ss))));
            }
        num += __shfl_xor(num, 32, 64);
        ss  += __shfl_xor(ss, 32, 64);
        if (h == 0) outp[m] = num / (fmaxf(sqrtf(ss), 1e-8f) * tn) * 10.0f;
    };

    // ---- prologue: bias/tvec staging overlaps idx loads; double-buffer first two gathers ----
    for (int t = tid; t < 448; t += 256) lds[t] = ((const uint32_t*)(ws + WS_B_OFF))[t];
    gissue(gx,  sv2);
    gissue(gx2, sv3);
    gpack(gx);                       // waits s2 only (issued before s3)
    __syncthreads();
    tn = *(const float*)(ws + WS_TN_OFF);

#pragma unroll 1
    for (int op = 0; op < 24; ++op) {
        const uint32_t cw = PROG[op];
        const int g   = cw & 7;
        const int u   = (cw >> 3) & 7;
        const int sH  = (cw >> 6) & 1;
        const int ini = (cw >> 7) & 1;
        const int bid = (cw >> 8) & 7;
        const int ep  = (cw >> 11) & 3;
        const int rd  = (cw >> 13) & 3;
        const int sl  = (cw >> 15) & 1;
        const int pg  = (cw >> 16) & 7;
        const int alt = (cw >> 19) & 1;

        if (g) gpack(alt ? gx2 : gx);

        if (ini) {
#pragma unroll
            for (int nt = 0; nt < 2; ++nt)
#pragma unroll
                for (int g2 = 0; g2 < 4; ++g2) {
                    const float4 b4 = *(const float4*)(ldsb + bid * 64 + nt * 32 + g2 * 8 + h * 4);
                    acc[nt][4 * g2 + 0] = b4.x; acc[nt][4 * g2 + 1] = b4.y;
                    acc[nt][4 * g2 + 2] = b4.z; acc[nt][4 * g2 + 3] = b4.w;
                }
        }

        __builtin_amdgcn_s_setprio(1);
        if (sH) uaH(u, sl ? slot1 : slot0);
        else    uaP(u);
        __builtin_amdgcn_s_setprio(0);

        if (pg) {   // issue next gather AFTER this op's weight loads (vmcnt is in-order)
            int idx;
            switch (pg) {
                case 1: idx = sv0; break;
                case 2: idx = sv1; break;
                case 3: idx = sv2; break;
                case 4: idx = sv3; break;
                case 5: idx = sv4; break;
                case 6: idx = ipv; break;
                default: idx = imv; break;
            }
            gissue(gx, idx);
        }

        if (ep == 1)      epiX(true);
        else if (ep == 2) epiX(false);
        else if (ep == 3) epiB(sl ? slot1 : slot0);

        if (rd == 1)      reduce(out + rowbase);
        else if (rd == 2) reduce(out + BATCH + rowbase);
    }
}

extern "C" void kernel_launch(void* const* d_in, const int* in_sizes, int n_in,
                              void* d_out, int out_size, void* d_ws, size_t ws_size,
                              hipStream_t stream) {
    const int*   seq  = (const int*)  d_in[0];
    const int*   post = (const int*)  d_in[1];
    const int*   negt = (const int*)  d_in[2];
    const float* E    = (const float*)d_in[3];
    const float* tv   = (const float*)d_in[4];
    const float* nW1  = (const float*)d_in[5];
    const float* nb1  = (const float*)d_in[6];
    const float* nW2  = (const float*)d_in[7];
    const float* nb2  = (const float*)d_in[8];
    const float* aW1  = (const float*)d_in[9];
    const float* ab1  = (const float*)d_in[10];
    const float* aW2  = (const float*)d_in[11];
    const float* ab2  = (const float*)d_in[12];
    const float* oW1  = (const float*)d_in[13];
    const float* ob1  = (const float*)d_in[14];
    const float* oW2  = (const float*)d_in[15];
    const float* ob2  = (const float*)d_in[16];
    float* out = (float*)d_out;
    char*  ws  = (char*)d_ws;   // uses ~67.3 KB

    hipLaunchKernelGGL(prep_kernel, dim3(130), dim3(256), 0, stream,
                       tv, nW1, nW2, aW1, aW2, oW1, oW2,
                       nb1, nb2, ab1, ab2, ob1, ob2, ws);
    hipLaunchKernelGGL(logicnet_mfma, dim3(BATCH / 128), dim3(256), 0, stream,
                       seq, post, negt, E, ws, out);
}

// Round 3
// 481.826 us; speedup vs baseline: 1.2097x; 1.2097x over previous
//
#include <hip/hip_runtime.h>
#include <stdint.h>
#include <math.h>

#define BATCH 131072
#define WS_TN_OFF 65536
#define WS_B_OFF  65544   // 6 x 64 floats: nb1,nb2,ab1,ab2,ob1,ob2 ; tvec at +1536 bytes

typedef __attribute__((ext_vector_type(8)))  short short8;   // 8 bf16
typedef __attribute__((ext_vector_type(16))) float float16;  // MFMA 32x32 acc
typedef __attribute__((ext_vector_type(2)))  unsigned int uint2v;

union S8 { short8 s; uint32_t u[4]; };
union F8 { float f[8]; uint32_t u[8]; float4 v4[2]; };

// ---------------- prep: weights -> bf16 (RNE) frag order; biases + tvec + |tvec| ----------------
// Frag layout (identical for A- and B-operand use of mfma_f32_32x32x16_bf16):
// lane -> n = nt*32+(lane&31); k = kc*16 + (lane>>5)*8 + j.
// ws: u*8192 + (kc*2+nt)*1024 + lane*16 + j*2. units u: 0=nW1 1=nW2 2=aW1[0:64] 3=aW1[64:128]
// 4=aW2 5=oW1[0:64] 6=oW1[64:128] 7=oW2
__global__ __launch_bounds__(256)
void prep_kernel(const float* __restrict__ tvec,
                 const float* __restrict__ nW1, const float* __restrict__ nW2,
                 const float* __restrict__ aW1, const float* __restrict__ aW2,
                 const float* __restrict__ oW1, const float* __restrict__ oW2,
                 const float* __restrict__ nb1, const float* __restrict__ nb2,
                 const float* __restrict__ ab1, const float* __restrict__ ab2,
                 const float* __restrict__ ob1, const float* __restrict__ ob2,
                 char* __restrict__ ws)
{
    const int id = blockIdx.x * 256 + threadIdx.x;
    if (id == 0) {
        float s = 0.f;
        for (int j = 0; j < 64; ++j) s = fmaf(tvec[j], tvec[j], s);
        *(float*)(ws + WS_TN_OFF) = fmaxf(sqrtf(s), 1e-8f);
    }
    if (id < 32768) {
        const float* srcs[8] = { nW1, nW2, aW1, aW1 + 4096, aW2, oW1, oW1 + 4096, oW2 };
        const int u    = id >> 12;
        const int e    = id & 4095;
        const int j    = e & 7;
        const int lane = (e >> 3) & 63;
        const int f    = e >> 9;          // kc*2 + nt
        const int nt   = f & 1, kc = f >> 1;
        const int k    = kc * 16 + (lane >> 5) * 8 + j;
        const int n    = nt * 32 + (lane & 31);
        const uint32_t b = __float_as_uint(srcs[u][k * 64 + n]);
        const uint32_t r = b + 0x7fffu + ((b >> 16) & 1u);   // RNE to bf16
        ((uint16_t*)(ws + u * 8192 + f * 1024 + lane * 16))[j] = (uint16_t)(r >> 16);
    } else if (id < 33152) {
        const int b   = id - 32768;       // 0..383
        const int arr = b >> 6, j = b & 63;
        const float* bp = (arr == 0) ? nb1 : (arr == 1) ? nb2 : (arr == 2) ? ab1
                        : (arr == 3) ? ab2 : (arr == 4) ? ob1 : ob2;
        ((float*)(ws + WS_B_OFF))[b] = bp[j];
    } else if (id < 33216) {
        const int j = id - 33152;         // 0..63: tvec copy
        ((float*)(ws + WS_B_OFF + 1536))[j] = tvec[j];
    }
}

// ---------------- main kernel: transposed MFMA (Y^T = W^T @ X^T), register dataflow +
//                  single-buffer gather prefetch + per-wave LDS slots (conflict-free) ----------
// op word: g(0) | u(3:5) | sH(6) | init(7) | bid(8:10) | epi(11:12) | red(13:14) | slot(15)
//          | pg(16:18)
// g : 1 -> pack prefetched gather buffer gx -> X frags (before MFMA)
// pg: 0 none, 1..5 issue gather of seq[:,pg-1], 6 pos_target, 7 neg_target (into gx, AFTER MFMA)
// sH: consume stored bf16 frag from LDS slot (sl: 0=i6, 1=enc) with 8 MFMA
// epi: 0 none, 1 act->X, 2 raw->X (hi/lo frags), 3 raw->LDS slot (bf16 RNE)
// red: 0 none, 1 reduce->out[pos], 2 reduce->out[neg]
#define OPW(g,u,sH,ini,bid,ep,rd,sl,pg) \
    ((g)|((u)<<3)|((sH)<<6)|((ini)<<7)|((bid)<<8)|((ep)<<11)|((rd)<<13)|((sl)<<15)|((pg)<<16))

__global__ __launch_bounds__(256, 3)
void logicnet_mfma(const int* __restrict__ seq, const int* __restrict__ post,
                   const int* __restrict__ negt, const float* __restrict__ E,
                   const char* __restrict__ ws, float* __restrict__ out)
{
    static const uint32_t PROG[24] = {
        OPW(0,5,0,1,4,0,0,0,0),  //  1: acc=ob1 + oW1[0:]^T@X(s2, packed in prologue)
        OPW(1,6,0,0,0,1,0,0,2),  //  2: pack s3; += oW1[64:]^T@X; issue s1; act -> X = h(i6)
        OPW(0,7,0,1,5,3,0,0,0),  //  3: acc=ob2 + oW2^T@X, raw -> i6 slot (LDS)
        OPW(1,0,0,1,0,1,0,0,1),  //  4: pack s1; acc=nb1 + nW1^T@X; issue s0; act -> X
        OPW(0,1,0,1,1,2,0,0,0),  //  5: acc=nb2 + nW2^T@X, raw -> X = n1
        OPW(0,3,0,1,2,0,0,0,0),  //  6: acc=ab1 + aW1[64:]^T@n1
        OPW(1,2,0,0,0,1,0,0,0),  //  7: pack s0; += aW1[0:]^T@X, act -> X = h(i5)
        OPW(0,4,0,1,3,2,0,0,0),  //  8: acc=ab2 + aW2^T@X, raw -> X = i5
        OPW(0,2,0,1,2,0,0,0,0),  //  9: acc=ab1 + aW1[0:]^T@i5
        OPW(0,3,1,0,0,1,0,0,0),  // 10: += aW1[64:]^T@i6slot, act -> X = h(i7)
        OPW(0,4,0,1,3,2,0,0,0),  // 11: acc=ab2 + aW2^T@X, raw -> X = i7
        OPW(0,0,0,1,0,1,0,0,5),  // 12: acc=nb1 + nW1^T@X; issue s4; act -> X
        OPW(0,1,0,1,1,2,0,0,0),  // 13: acc=nb2 + nW2^T@X, raw -> X = n7
        OPW(0,5,0,1,4,0,0,0,0),  // 14: acc=ob1 + oW1[0:]^T@n7
        OPW(1,6,0,0,0,1,0,0,0),  // 15: pack s4; += oW1[64:]^T@X, act -> X
        OPW(0,7,0,1,5,2,0,0,0),  // 16: acc=ob2 + oW2^T@X, raw -> X = out8
        OPW(0,0,0,1,0,1,0,0,6),  // 17: acc=nb1 + nW1^T@X; issue ip; act -> X
        OPW(0,1,0,1,1,3,0,1,0),  // 18: acc=nb2 + nW2^T@X, raw -> enc slot (LDS)
        OPW(0,5,1,1,4,0,0,1,0),  // 19: acc=ob1 + oW1[0:]^T@encslot
        OPW(1,6,0,0,0,1,0,0,7),  // 20: pack ip; += oW1[64:]^T@X; issue im; act -> X
        OPW(0,7,0,1,5,0,1,0,0),  // 21: acc=ob2 + oW2^T@X, reduce -> out(pos)
        OPW(0,5,1,1,4,0,0,1,0),  // 22: acc=ob1 + oW1[0:]^T@encslot  (recompute)
        OPW(1,6,0,0,0,1,0,0,0),  // 23: pack im; += oW1[64:]^T@X, act -> X
        OPW(0,7,0,1,5,0,2,0,0),  // 24: acc=ob2 + oW2^T@X, reduce -> out(neg)
    };

    // LDS: biases[384]+tvec[64] + per-wave i6 slot (4 KB/wave) + per-wave enc slot (4 KB/wave)
    __shared__ uint32_t lds[448 + 4096 + 4096];   // 33.8 KB
    const int tid  = threadIdx.x;
    const int wid  = tid >> 6;
    const int lane = tid & 63;
    const int m    = lane & 31;            // batch row within tile (= C column)
    const int h    = lane >> 5;            // half selector
    const int rowbase = (blockIdx.x * 4 + wid) * 32;
    const int rr   = rowbase + m;

    uint32_t* const slot0 = &lds[448 + wid * 1024];          // i6
    uint32_t* const slot1 = &lds[448 + 4096 + wid * 1024];   // enc
    const float* const ldsb = (const float*)lds;             // biases [6][64]
    const float* const ltv  = (const float*)(lds + 384);     // tvec [64]

    const int sv0 = seq[(size_t)rr * 5 + 0], sv1 = seq[(size_t)rr * 5 + 1];
    const int sv2 = seq[(size_t)rr * 5 + 2], sv3 = seq[(size_t)rr * 5 + 3];
    const int sv4 = seq[(size_t)rr * 5 + 4];
    const int ipv = post[rr], imv = negt[rr];

    float16 acc[2];                 // C layout: col = lane&31 = batch, row = feature
    S8 xhi[4], xlo[4];              // current X as B-frags (hi/lo fp32-emulation)
    F8 gx[4];                       // single raw gather prefetch buffer
    float tn;

    // issue 8x float4 loads of one embedding row slice into gx (no wait here)
    auto gissue = [&](int idx) {
        const float4* e = (const float4*)(E + (size_t)idx * 64 + h * 8);
#pragma unroll
        for (int kc = 0; kc < 4; ++kc) { gx[kc].v4[0] = e[kc * 4]; gx[kc].v4[1] = e[kc * 4 + 1]; }
    };
    // pack gx -> xhi/xlo B-frags (hi = truncate, lo = residual)
    auto gpack = [&]() {
#pragma unroll
        for (int kc = 0; kc < 4; ++kc) {
#pragma unroll
            for (int w = 0; w < 4; ++w) {
                const uint32_t b0 = gx[kc].u[2 * w], b1 = gx[kc].u[2 * w + 1];
                xhi[kc].u[w] = __builtin_amdgcn_perm(b1, b0, 0x07060302u);
                const float l0 = gx[kc].f[2 * w]     - __uint_as_float(b0 & 0xffff0000u);
                const float l1 = gx[kc].f[2 * w + 1] - __uint_as_float(b1 & 0xffff0000u);
                xlo[kc].u[w] = __builtin_amdgcn_perm(__float_as_uint(l1), __float_as_uint(l0), 0x07060302u);
            }
        }
    };

    // acc += W(u)^T @ X(hi|lo): 16 MFMA, W in the A slot, X in the B slot
    auto uaP = [&](int u) {
        const char* wb = ws + u * 8192 + lane * 16;
#pragma unroll
        for (int kc = 0; kc < 4; ++kc) {
            const short8 w0 = *(const short8*)(wb + (kc * 2 + 0) * 1024);
            const short8 w1 = *(const short8*)(wb + (kc * 2 + 1) * 1024);
            acc[0] = __builtin_amdgcn_mfma_f32_32x32x16_bf16(w0, xhi[kc].s, acc[0], 0, 0, 0);
            acc[1] = __builtin_amdgcn_mfma_f32_32x32x16_bf16(w1, xhi[kc].s, acc[1], 0, 0, 0);
            acc[0] = __builtin_amdgcn_mfma_f32_32x32x16_bf16(w0, xlo[kc].s, acc[0], 0, 0, 0);
            acc[1] = __builtin_amdgcn_mfma_f32_32x32x16_bf16(w1, xlo[kc].s, acc[1], 0, 0, 0);
        }
    };

    // acc += W(u)^T @ LDS-stored bf16 frag: 8 MFMA.
    // Slot layout [kc][lane]: 16B per lane, 16B lane stride -> conflict-free b128 pattern.
    auto uaH = [&](int u, const uint32_t* slot) {
        const char* wb = ws + u * 8192 + lane * 16;
#pragma unroll
        for (int kc = 0; kc < 4; ++kc) {
            const short8 xf = *(const short8*)(slot + kc * 256 + lane * 4);
            const short8 w0 = *(const short8*)(wb + (kc * 2 + 0) * 1024);
            const short8 w1 = *(const short8*)(wb + (kc * 2 + 1) * 1024);
            acc[0] = __builtin_amdgcn_mfma_f32_32x32x16_bf16(w0, xf, acc[0], 0, 0, 0);
            acc[1] = __builtin_amdgcn_mfma_f32_32x32x16_bf16(w1, xf, acc[1], 0, 0, 0);
        }
    };

    // C -> next B-frags, in-register (permlane32_swap pairs quads across the h-halves)
    auto epiX = [&](bool act) {
#pragma unroll
        for (int nt = 0; nt < 2; ++nt) {
#pragma unroll
            for (int c = 0; c < 2; ++c) {
                uint32_t ph[2][2], pl[2][2];
#pragma unroll
                for (int d = 0; d < 2; ++d) {
                    const int g2 = 2 * c + d;
                    float v0 = acc[nt][4 * g2 + 0], v1 = acc[nt][4 * g2 + 1];
                    float v2 = acc[nt][4 * g2 + 2], v3 = acc[nt][4 * g2 + 3];
                    if (act) {
                        v0 = fmaxf(v0, 0.01f * v0); v1 = fmaxf(v1, 0.01f * v1);
                        v2 = fmaxf(v2, 0.01f * v2); v3 = fmaxf(v3, 0.01f * v3);
                    }
                    const uint32_t b0 = __float_as_uint(v0), b1 = __float_as_uint(v1);
                    const uint32_t b2 = __float_as_uint(v2), b3 = __float_as_uint(v3);
                    ph[d][0] = __builtin_amdgcn_perm(b1, b0, 0x07060302u);
                    ph[d][1] = __builtin_amdgcn_perm(b3, b2, 0x07060302u);
                    const float l0 = v0 - __uint_as_float(b0 & 0xffff0000u);
                    const float l1 = v1 - __uint_as_float(b1 & 0xffff0000u);
                    const float l2 = v2 - __uint_as_float(b2 & 0xffff0000u);
                    const float l3 = v3 - __uint_as_float(b3 & 0xffff0000u);
                    pl[d][0] = __builtin_amdgcn_perm(__float_as_uint(l1), __float_as_uint(l0), 0x07060302u);
                    pl[d][1] = __builtin_amdgcn_perm(__float_as_uint(l3), __float_as_uint(l2), 0x07060302u);
                }
                const int kc = 2 * nt + c;
#pragma unroll
                for (int w = 0; w < 2; ++w) {
                    uint2v rh = __builtin_amdgcn_permlane32_swap(ph[0][w], ph[1][w], false, false);
                    xhi[kc].u[w]     = rh[0];
                    xhi[kc].u[2 + w] = rh[1];
                    uint2v rl = __builtin_amdgcn_permlane32_swap(pl[0][w], pl[1][w], false, false);
                    xlo[kc].u[w]     = rl[0];
                    xlo[kc].u[2 + w] = rl[1];
                }
            }
        }
    };

    // C -> stored bf16 frag (RNE) into per-wave LDS slot ([kc][lane] layout, conflict-free)
    auto epiB = [&](uint32_t* slot) {
#pragma unroll
        for (int nt = 0; nt < 2; ++nt) {
#pragma unroll
            for (int c = 0; c < 2; ++c) {
                uint32_t pp[2][2];
#pragma unroll
                for (int d = 0; d < 2; ++d) {
                    const int g2 = 2 * c + d;
                    asm("v_cvt_pk_bf16_f32 %0, %1, %2"
                        : "=v"(pp[d][0]) : "v"(acc[nt][4 * g2 + 0]), "v"(acc[nt][4 * g2 + 1]));
                    asm("v_cvt_pk_bf16_f32 %0, %1, %2"
                        : "=v"(pp[d][1]) : "v"(acc[nt][4 * g2 + 2]), "v"(acc[nt][4 * g2 + 3]));
                }
                const int kc = 2 * nt + c;
                S8 o;
#pragma unroll
                for (int w = 0; w < 2; ++w) {
                    uint2v r = __builtin_amdgcn_permlane32_swap(pp[0][w], pp[1][w], false, false);
                    o.u[w]     = r[0];
                    o.u[2 + w] = r[1];
                }
                *(short8*)(slot + kc * 256 + lane * 4) = o.s;
            }
        }
    };

    // cosine head: lane already holds its batch row's features
    auto reduce = [&](float* outp) {
        float num = 0.f, ss = 0.f;
#pragma unroll
        for (int nt = 0; nt < 2; ++nt)
#pragma unroll
            for (int g2 = 0; g2 < 4; ++g2) {
                const float4 t4 = *(const float4*)(ltv + nt * 32 + g2 * 8 + h * 4);
                const float y0 = acc[nt][4 * g2 + 0], y1 = acc[nt][4 * g2 + 1];
                const float y2 = acc[nt][4 * g2 + 2], y3 = acc[nt][4 * g2 + 3];
                num = fmaf(y0, t4.x, fmaf(y1, t4.y, fmaf(y2, t4.z, fmaf(y3, t4.w, num))));
                ss  = fmaf(y0, y0, fmaf(y1, y1, fmaf(y2, y2, fmaf(y3, y3, ss))));
            }
        num += __shfl_xor(num, 32, 64);
        ss  += __shfl_xor(ss, 32, 64);
        if (h == 0) outp[m] = num / (fmaxf(sqrtf(ss), 1e-8f) * tn) * 10.0f;
    };

    // ---- prologue: bias/tvec staging + s2 gather BEFORE the barrier (its vmcnt(0) drain
    //      absorbs the gather latency); then pack s2 and prefetch s3 into the freed gx ----
    for (int t = tid; t < 448; t += 256) lds[t] = ((const uint32_t*)(ws + WS_B_OFF))[t];
    gissue(sv2);
    __syncthreads();
    tn = *(const float*)(ws + WS_TN_OFF);
    gpack();                         // X = s2
    gissue(sv3);                     // prefetch s3 (covered by op 1)

#pragma unroll 1
    for (int op = 0; op < 24; ++op) {
        const uint32_t cw = PROG[op];
        const int g   = cw & 7;
        const int u   = (cw >> 3) & 7;
        const int sH  = (cw >> 6) & 1;
        const int ini = (cw >> 7) & 1;
        const int bid = (cw >> 8) & 7;
        const int ep  = (cw >> 11) & 3;
        const int rd  = (cw >> 13) & 3;
        const int sl  = (cw >> 15) & 1;
        const int pg  = (cw >> 16) & 7;

        if (g) gpack();

        if (ini) {
#pragma unroll
            for (int nt = 0; nt < 2; ++nt)
#pragma unroll
                for (int g2 = 0; g2 < 4; ++g2) {
                    const float4 b4 = *(const float4*)(ldsb + bid * 64 + nt * 32 + g2 * 8 + h * 4);
                    acc[nt][4 * g2 + 0] = b4.x; acc[nt][4 * g2 + 1] = b4.y;
                    acc[nt][4 * g2 + 2] = b4.z; acc[nt][4 * g2 + 3] = b4.w;
                }
        }

        __builtin_amdgcn_s_setprio(1);
        if (sH) uaH(u, sl ? slot1 : slot0);
        else    uaP(u);
        __builtin_amdgcn_s_setprio(0);

        if (pg) {   // issue next gather AFTER this op's MFMAs (gx was freed by this op's pack)
            int idx;
            switch (pg) {
                case 1: idx = sv0; break;
                case 2: idx = sv1; break;
                case 3: idx = sv2; break;
                case 4: idx = sv3; break;
                case 5: idx = sv4; break;
                case 6: idx = ipv; break;
                default: idx = imv; break;
            }
            gissue(idx);
        }

        if (ep == 1)      epiX(true);
        else if (ep == 2) epiX(false);
        else if (ep == 3) epiB(sl ? slot1 : slot0);

        if (rd == 1)      reduce(out + rowbase);
        else if (rd == 2) reduce(out + BATCH + rowbase);
    }
}

extern "C" void kernel_launch(void* const* d_in, const int* in_sizes, int n_in,
                              void* d_out, int out_size, void* d_ws, size_t ws_size,
                              hipStream_t stream) {
    const int*   seq  = (const int*)  d_in[0];
    const int*   post = (const int*)  d_in[1];
    const int*   negt = (const int*)  d_in[2];
    const float* E    = (const float*)d_in[3];
    const float* tv   = (const float*)d_in[4];
    const float* nW1  = (const float*)d_in[5];
    const float* nb1  = (const float*)d_in[6];
    const float* nW2  = (const float*)d_in[7];
    const float* nb2  = (const float*)d_in[8];
    const float* aW1  = (const float*)d_in[9];
    const float* ab1  = (const float*)d_in[10];
    const float* aW2  = (const float*)d_in[11];
    const float* ab2  = (const float*)d_in[12];
    const float* oW1  = (const float*)d_in[13];
    const float* ob1  = (const float*)d_in[14];
    const float* oW2  = (const float*)d_in[15];
    const float* ob2  = (const float*)d_in[16];
    float* out = (float*)d_out;
    char*  ws  = (char*)d_ws;   // uses ~67.3 KB

    hipLaunchKernelGGL(prep_kernel, dim3(130), dim3(256), 0, stream,
                       tv, nW1, nW2, aW1, aW2, oW1, oW2,
                       nb1, nb2, ab1, ab2, ob1, ob2, ws);
    hipLaunchKernelGGL(logicnet_mfma, dim3(BATCH / 128), dim3(256), 0, stream,
                       seq, post, negt, E, ws, out);
}

// Round 4
// 396.031 us; speedup vs baseline: 1.4718x; 1.2166x over previous
//
#include <hip/hip_runtime.h>
#include <stdint.h>
#include <math.h>

#define BATCH 131072
#define WS_TN_OFF 65536
#define WS_B_OFF  65544   // 6 x 64 floats: nb1,nb2,ab1,ab2,ob1,ob2 ; tvec at +1536 bytes

typedef __attribute__((ext_vector_type(8)))  short short8;   // 8 bf16
typedef __attribute__((ext_vector_type(16))) float float16;  // MFMA 32x32 acc
typedef __attribute__((ext_vector_type(2)))  unsigned int uint2v;

union S8 { short8 s; uint32_t u[4]; };
union F8 { float f[8]; uint32_t u[8]; float4 v4[2]; };

// ---------------- prep: weights -> bf16 (RNE) frag order; biases + tvec + |tvec| ----------------
// Frag layout (identical for A- and B-operand use of mfma_f32_32x32x16_bf16):
// lane -> n = nt*32+(lane&31); k = kc*16 + (lane>>5)*8 + j.
// ws: u*8192 + (kc*2+nt)*1024 + lane*16 + j*2. units u: 0=nW1 1=nW2 2=aW1[0:64] 3=aW1[64:128]
// 4=aW2 5=oW1[0:64] 6=oW1[64:128] 7=oW2
__global__ __launch_bounds__(256)
void prep_kernel(const float* __restrict__ tvec,
                 const float* __restrict__ nW1, const float* __restrict__ nW2,
                 const float* __restrict__ aW1, const float* __restrict__ aW2,
                 const float* __restrict__ oW1, const float* __restrict__ oW2,
                 const float* __restrict__ nb1, const float* __restrict__ nb2,
                 const float* __restrict__ ab1, const float* __restrict__ ab2,
                 const float* __restrict__ ob1, const float* __restrict__ ob2,
                 char* __restrict__ ws)
{
    const int id = blockIdx.x * 256 + threadIdx.x;
    if (id == 0) {
        float s = 0.f;
        for (int j = 0; j < 64; ++j) s = fmaf(tvec[j], tvec[j], s);
        *(float*)(ws + WS_TN_OFF) = fmaxf(sqrtf(s), 1e-8f);
    }
    if (id < 32768) {
        const float* srcs[8] = { nW1, nW2, aW1, aW1 + 4096, aW2, oW1, oW1 + 4096, oW2 };
        const int u    = id >> 12;
        const int e    = id & 4095;
        const int j    = e & 7;
        const int lane = (e >> 3) & 63;
        const int f    = e >> 9;          // kc*2 + nt
        const int nt   = f & 1, kc = f >> 1;
        const int k    = kc * 16 + (lane >> 5) * 8 + j;
        const int n    = nt * 32 + (lane & 31);
        const uint32_t b = __float_as_uint(srcs[u][k * 64 + n]);
        const uint32_t r = b + 0x7fffu + ((b >> 16) & 1u);   // RNE to bf16
        ((uint16_t*)(ws + u * 8192 + f * 1024 + lane * 16))[j] = (uint16_t)(r >> 16);
    } else if (id < 33152) {
        const int b   = id - 32768;       // 0..383
        const int arr = b >> 6, j = b & 63;
        const float* bp = (arr == 0) ? nb1 : (arr == 1) ? nb2 : (arr == 2) ? ab1
                        : (arr == 3) ? ab2 : (arr == 4) ? ob1 : ob2;
        ((float*)(ws + WS_B_OFF))[b] = bp[j];
    } else if (id < 33216) {
        const int j = id - 33152;         // 0..63: tvec copy
        ((float*)(ws + WS_B_OFF + 1536))[j] = tvec[j];
    }
}

// ---------------- main kernel: transposed MFMA (Y^T = W^T @ X^T), register-diet dataflow ------
// X state: hi-half (bf16 truncation) in 16 VGPRs; lo-half (residual bf16) in per-wave LDS.
// Stored bf16 intermediates i6/enc share ONE per-wave LDS slot (disjoint lifetimes).
// Gathers point-of-use, streamed in two 16-float halves (<=16 transient VGPRs).
// op word: g(0:2) | u(3:5) | sH(6) | init(7) | bid(8:10) | epi(11:12) | red(13:14)
// g: 0 none, 1..5 seq[:,g-1], 6 pos_target, 7 neg_target  (gather -> X)
// sH: consume stored bf16 frag from the shared LDS slot with 8 MFMA
// epi: 0 none, 1 act->X, 2 raw->X, 3 raw->slot (bf16 RNE)
// red: 0 none, 1 reduce->out[pos], 2 reduce->out[neg]
#define OPW(g,u,sH,ini,bid,ep,rd) \
    ((g)|((u)<<3)|((sH)<<6)|((ini)<<7)|((bid)<<8)|((ep)<<11)|((rd)<<13))

__global__ __launch_bounds__(256, 4)
void logicnet_mfma(const int* __restrict__ seq, const int* __restrict__ post,
                   const int* __restrict__ negt, const float* __restrict__ E,
                   const char* __restrict__ ws, float* __restrict__ out)
{
    static const uint32_t PROG[24] = {
        OPW(0,5,0,1,4,0,0),  //  1: acc=ob1 + oW1[0:]^T@X(s2, packed in prologue)
        OPW(4,6,0,0,0,1,0),  //  2: gather s3; += oW1[64:]^T@X, act -> X = h(i6)
        OPW(0,7,0,1,5,3,0),  //  3: acc=ob2 + oW2^T@X, raw -> slot (i6)
        OPW(2,0,0,1,0,1,0),  //  4: gather s1; acc=nb1 + nW1^T@X, act -> X
        OPW(0,1,0,1,1,2,0),  //  5: acc=nb2 + nW2^T@X, raw -> X = n1
        OPW(0,3,0,1,2,0,0),  //  6: acc=ab1 + aW1[64:]^T@n1
        OPW(1,2,0,0,0,1,0),  //  7: gather s0; += aW1[0:]^T@X, act -> X = h(i5)
        OPW(0,4,0,1,3,2,0),  //  8: acc=ab2 + aW2^T@X, raw -> X = i5
        OPW(0,2,0,1,2,0,0),  //  9: acc=ab1 + aW1[0:]^T@i5
        OPW(0,3,1,0,0,1,0),  // 10: += aW1[64:]^T@slot(i6), act -> X = h(i7)
        OPW(0,4,0,1,3,2,0),  // 11: acc=ab2 + aW2^T@X, raw -> X = i7
        OPW(0,0,0,1,0,1,0),  // 12: acc=nb1 + nW1^T@X, act -> X
        OPW(0,1,0,1,1,2,0),  // 13: acc=nb2 + nW2^T@X, raw -> X = n7
        OPW(0,5,0,1,4,0,0),  // 14: acc=ob1 + oW1[0:]^T@n7
        OPW(5,6,0,0,0,1,0),  // 15: gather s4; += oW1[64:]^T@X, act -> X
        OPW(0,7,0,1,5,2,0),  // 16: acc=ob2 + oW2^T@X, raw -> X = out8
        OPW(0,0,0,1,0,1,0),  // 17: acc=nb1 + nW1^T@X, act -> X
        OPW(0,1,0,1,1,3,0),  // 18: acc=nb2 + nW2^T@X, raw -> slot (enc; i6 dead)
        OPW(0,5,1,1,4,0,0),  // 19: acc=ob1 + oW1[0:]^T@slot(enc)
        OPW(6,6,0,0,0,1,0),  // 20: gather ip; += oW1[64:]^T@X, act -> X
        OPW(0,7,0,1,5,0,1),  // 21: acc=ob2 + oW2^T@X, reduce -> out(pos)
        OPW(0,5,1,1,4,0,0),  // 22: acc=ob1 + oW1[0:]^T@slot(enc)  (recompute)
        OPW(7,6,0,0,0,1,0),  // 23: gather im; += oW1[64:]^T@X, act -> X
        OPW(0,7,0,1,5,0,2),  // 24: acc=ob2 + oW2^T@X, reduce -> out(neg)
    };

    // LDS: biases[384]+tvec[64] + per-wave shared slot (4 KB) + per-wave xlo tile (4 KB)
    __shared__ uint32_t lds[448 + 4096 + 4096];   // 34.6 KB -> 4 blocks/CU
    const int tid  = threadIdx.x;
    const int wid  = tid >> 6;
    const int lane = tid & 63;
    const int m    = lane & 31;            // batch row within tile (= C column)
    const int h    = lane >> 5;            // half selector
    const int rowbase = (blockIdx.x * 4 + wid) * 32;
    const int rr   = rowbase + m;

    uint32_t* const slot = &lds[448 + wid * 1024];          // stored bf16 frag (i6 then enc)
    uint32_t* const xloL = &lds[448 + 4096 + wid * 1024];   // X lo-residual tile
    const float* const ldsb = (const float*)lds;            // biases [6][64]
    const float* const ltv  = (const float*)(lds + 384);    // tvec [64]

    const int sv0 = seq[(size_t)rr * 5 + 0], sv1 = seq[(size_t)rr * 5 + 1];
    const int sv2 = seq[(size_t)rr * 5 + 2], sv3 = seq[(size_t)rr * 5 + 3];
    const int sv4 = seq[(size_t)rr * 5 + 4];
    const int ipv = post[rr], imv = negt[rr];

    float16 acc[2];                 // C layout: col = lane&31 = batch, row = feature
    S8 xhi[4];                      // X hi-half B-frags (bf16 truncation), 16 VGPRs
    float tn;

    // pack one kc's 8 raw floats -> xhi regs + xlo LDS ([kc][lane] layout, conflict-free b128)
    auto packkc = [&](const F8& t, int kc) {
        S8 lo;
#pragma unroll
        for (int w = 0; w < 4; ++w) {
            const uint32_t b0 = t.u[2 * w], b1 = t.u[2 * w + 1];
            xhi[kc].u[w] = __builtin_amdgcn_perm(b1, b0, 0x07060302u);   // (hi(b1)<<16)|hi(b0)
            const float l0 = t.f[2 * w]     - __uint_as_float(b0 & 0xffff0000u);
            const float l1 = t.f[2 * w + 1] - __uint_as_float(b1 & 0xffff0000u);
            lo.u[w] = __builtin_amdgcn_perm(__float_as_uint(l1), __float_as_uint(l0), 0x07060302u);
        }
        *(short8*)(xloL + kc * 256 + lane * 4) = lo.s;
    };

    // embedding gather -> X, streamed in two 16-float halves (<=16 transient VGPRs)
    auto gw = [&](int idx) {
        const float4* e = (const float4*)(E + (size_t)idx * 64 + h * 8);
#pragma unroll
        for (int hp = 0; hp < 2; ++hp) {
            F8 t0, t1;
            t0.v4[0] = e[(2 * hp) * 4];     t0.v4[1] = e[(2 * hp) * 4 + 1];
            t1.v4[0] = e[(2 * hp + 1) * 4]; t1.v4[1] = e[(2 * hp + 1) * 4 + 1];
            packkc(t0, 2 * hp);
            packkc(t1, 2 * hp + 1);
        }
    };

    // acc += W(u)^T @ X(hi regs | lo LDS): 16 MFMA, xlo reads pipelined one kc ahead
    auto uaP = [&](int u) {
        const char* wb = ws + u * 8192 + lane * 16;
        S8 cur, nxt;
        cur.s = *(const short8*)(xloL + lane * 4);
#pragma unroll
        for (int kc = 0; kc < 4; ++kc) {
            if (kc < 3) nxt.s = *(const short8*)(xloL + (kc + 1) * 256 + lane * 4);
            const short8 w0 = *(const short8*)(wb + (kc * 2 + 0) * 1024);
            const short8 w1 = *(const short8*)(wb + (kc * 2 + 1) * 1024);
            acc[0] = __builtin_amdgcn_mfma_f32_32x32x16_bf16(w0, xhi[kc].s, acc[0], 0, 0, 0);
            acc[1] = __builtin_amdgcn_mfma_f32_32x32x16_bf16(w1, xhi[kc].s, acc[1], 0, 0, 0);
            acc[0] = __builtin_amdgcn_mfma_f32_32x32x16_bf16(w0, cur.s, acc[0], 0, 0, 0);
            acc[1] = __builtin_amdgcn_mfma_f32_32x32x16_bf16(w1, cur.s, acc[1], 0, 0, 0);
            cur = nxt;
        }
    };

    // acc += W(u)^T @ slot frag: 8 MFMA
    auto uaH = [&](int u) {
        const char* wb = ws + u * 8192 + lane * 16;
#pragma unroll
        for (int kc = 0; kc < 4; ++kc) {
            const short8 xf = *(const short8*)(slot + kc * 256 + lane * 4);
            const short8 w0 = *(const short8*)(wb + (kc * 2 + 0) * 1024);
            const short8 w1 = *(const short8*)(wb + (kc * 2 + 1) * 1024);
            acc[0] = __builtin_amdgcn_mfma_f32_32x32x16_bf16(w0, xf, acc[0], 0, 0, 0);
            acc[1] = __builtin_amdgcn_mfma_f32_32x32x16_bf16(w1, xf, acc[1], 0, 0, 0);
        }
    };

    // C -> next X (hi regs + lo LDS), permlane32_swap pairs quads across the h-halves
    auto epiX = [&](bool act) {
#pragma unroll
        for (int nt = 0; nt < 2; ++nt) {
#pragma unroll
            for (int c = 0; c < 2; ++c) {
                uint32_t ph[2][2], pl[2][2];
#pragma unroll
                for (int d = 0; d < 2; ++d) {
                    const int g2 = 2 * c + d;
                    float v0 = acc[nt][4 * g2 + 0], v1 = acc[nt][4 * g2 + 1];
                    float v2 = acc[nt][4 * g2 + 2], v3 = acc[nt][4 * g2 + 3];
                    if (act) {
                        v0 = fmaxf(v0, 0.01f * v0); v1 = fmaxf(v1, 0.01f * v1);
                        v2 = fmaxf(v2, 0.01f * v2); v3 = fmaxf(v3, 0.01f * v3);
                    }
                    const uint32_t b0 = __float_as_uint(v0), b1 = __float_as_uint(v1);
                    const uint32_t b2 = __float_as_uint(v2), b3 = __float_as_uint(v3);
                    ph[d][0] = __builtin_amdgcn_perm(b1, b0, 0x07060302u);
                    ph[d][1] = __builtin_amdgcn_perm(b3, b2, 0x07060302u);
                    const float l0 = v0 - __uint_as_float(b0 & 0xffff0000u);
                    const float l1 = v1 - __uint_as_float(b1 & 0xffff0000u);
                    const float l2 = v2 - __uint_as_float(b2 & 0xffff0000u);
                    const float l3 = v3 - __uint_as_float(b3 & 0xffff0000u);
                    pl[d][0] = __builtin_amdgcn_perm(__float_as_uint(l1), __float_as_uint(l0), 0x07060302u);
                    pl[d][1] = __builtin_amdgcn_perm(__float_as_uint(l3), __float_as_uint(l2), 0x07060302u);
                }
                const int kc = 2 * nt + c;
                S8 lo;
#pragma unroll
                for (int w = 0; w < 2; ++w) {
                    uint2v rh = __builtin_amdgcn_permlane32_swap(ph[0][w], ph[1][w], false, false);
                    xhi[kc].u[w]     = rh[0];
                    xhi[kc].u[2 + w] = rh[1];
                    uint2v rl = __builtin_amdgcn_permlane32_swap(pl[0][w], pl[1][w], false, false);
                    lo.u[w]     = rl[0];
                    lo.u[2 + w] = rl[1];
                }
                *(short8*)(xloL + kc * 256 + lane * 4) = lo.s;
            }
        }
    };

    // C -> stored bf16 frag (RNE) into the shared per-wave LDS slot
    auto epiB = [&]() {
#pragma unroll
        for (int nt = 0; nt < 2; ++nt) {
#pragma unroll
            for (int c = 0; c < 2; ++c) {
                uint32_t pp[2][2];
#pragma unroll
                for (int d = 0; d < 2; ++d) {
                    const int g2 = 2 * c + d;
                    asm("v_cvt_pk_bf16_f32 %0, %1, %2"
                        : "=v"(pp[d][0]) : "v"(acc[nt][4 * g2 + 0]), "v"(acc[nt][4 * g2 + 1]));
                    asm("v_cvt_pk_bf16_f32 %0, %1, %2"
                        : "=v"(pp[d][1]) : "v"(acc[nt][4 * g2 + 2]), "v"(acc[nt][4 * g2 + 3]));
                }
                const int kc = 2 * nt + c;
                S8 o;
#pragma unroll
                for (int w = 0; w < 2; ++w) {
                    uint2v r = __builtin_amdgcn_permlane32_swap(pp[0][w], pp[1][w], false, false);
                    o.u[w]     = r[0];
                    o.u[2 + w] = r[1];
                }
                *(short8*)(slot + kc * 256 + lane * 4) = o.s;
            }
        }
    };

    // cosine head: lane already holds its batch row's features
    auto reduce = [&](float* outp) {
        float num = 0.f, ss = 0.f;
#pragma unroll
        for (int nt = 0; nt < 2; ++nt)
#pragma unroll
            for (int g2 = 0; g2 < 4; ++g2) {
                const float4 t4 = *(const float4*)(ltv + nt * 32 + g2 * 8 + h * 4);
                const float y0 = acc[nt][4 * g2 + 0], y1 = acc[nt][4 * g2 + 1];
                const float y2 = acc[nt][4 * g2 + 2], y3 = acc[nt][4 * g2 + 3];
                num = fmaf(y0, t4.x, fmaf(y1, t4.y, fmaf(y2, t4.z, fmaf(y3, t4.w, num))));
                ss  = fmaf(y0, y0, fmaf(y1, y1, fmaf(y2, y2, fmaf(y3, y3, ss))));
            }
        num += __shfl_xor(num, 32, 64);
        ss  += __shfl_xor(ss, 32, 64);
        if (h == 0) outp[m] = num / (fmaxf(sqrtf(ss), 1e-8f) * tn) * 10.0f;
    };

    // ---- prologue: bias/tvec staging; first gather (s2) overlaps the barrier wait ----
    for (int t = tid; t < 448; t += 256) lds[t] = ((const uint32_t*)(ws + WS_B_OFF))[t];
    gw(sv2);                         // X = s2 (per-wave LDS region, safe pre-barrier)
    __syncthreads();
    tn = *(const float*)(ws + WS_TN_OFF);

#pragma unroll 1
    for (int op = 0; op < 24; ++op) {
        const uint32_t cw = PROG[op];
        const int g   = cw & 7;
        const int u   = (cw >> 3) & 7;
        const int sH  = (cw >> 6) & 1;
        const int ini = (cw >> 7) & 1;
        const int bid = (cw >> 8) & 7;
        const int ep  = (cw >> 11) & 3;
        const int rd  = (cw >> 13) & 3;

        if (g) {
            int idx;
            switch (g) {
                case 1: idx = sv0; break;
                case 2: idx = sv1; break;
                case 3: idx = sv2; break;
                case 4: idx = sv3; break;
                case 5: idx = sv4; break;
                case 6: idx = ipv; break;
                default: idx = imv; break;
            }
            gw(idx);
        }

        if (ini) {
#pragma unroll
            for (int nt = 0; nt < 2; ++nt)
#pragma unroll
                for (int g2 = 0; g2 < 4; ++g2) {
                    const float4 b4 = *(const float4*)(ldsb + bid * 64 + nt * 32 + g2 * 8 + h * 4);
                    acc[nt][4 * g2 + 0] = b4.x; acc[nt][4 * g2 + 1] = b4.y;
                    acc[nt][4 * g2 + 2] = b4.z; acc[nt][4 * g2 + 3] = b4.w;
                }
        }

        __builtin_amdgcn_s_setprio(1);
        if (sH) uaH(u);
        else    uaP(u);
        __builtin_amdgcn_s_setprio(0);

        if (ep == 1)      epiX(true);
        else if (ep == 2) epiX(false);
        else if (ep == 3) epiB();

        if (rd == 1)      reduce(out + rowbase);
        else if (rd == 2) reduce(out + BATCH + rowbase);
    }
}

extern "C" void kernel_launch(void* const* d_in, const int* in_sizes, int n_in,
                              void* d_out, int out_size, void* d_ws, size_t ws_size,
                              hipStream_t stream) {
    const int*   seq  = (const int*)  d_in[0];
    const int*   post = (const int*)  d_in[1];
    const int*   negt = (const int*)  d_in[2];
    const float* E    = (const float*)d_in[3];
    const float* tv   = (const float*)d_in[4];
    const float* nW1  = (const float*)d_in[5];
    const float* nb1  = (const float*)d_in[6];
    const float* nW2  = (const float*)d_in[7];
    const float* nb2  = (const float*)d_in[8];
    const float* aW1  = (const float*)d_in[9];
    const float* ab1  = (const float*)d_in[10];
    const float* aW2  = (const float*)d_in[11];
    const float* ab2  = (const float*)d_in[12];
    const float* oW1  = (const float*)d_in[13];
    const float* ob1  = (const float*)d_in[14];
    const float* oW2  = (const float*)d_in[15];
    const float* ob2  = (const float*)d_in[16];
    float* out = (float*)d_out;
    char*  ws  = (char*)d_ws;   // uses ~67.3 KB

    hipLaunchKernelGGL(prep_kernel, dim3(130), dim3(256), 0, stream,
                       tv, nW1, nW2, aW1, aW2, oW1, oW2,
                       nb1, nb2, ab1, ab2, ob1, ob2, ws);
    hipLaunchKernelGGL(logicnet_mfma, dim3(BATCH / 128), dim3(256), 0, stream,
                       seq, post, negt, E, ws, out);
}